// Round 1
// baseline (968.398 us; speedup 1.0000x reference)
//
#include <hip/hip_runtime.h>

#define HIDDEN 768
#define NQ 64
#define WINSZ 512
#define MSEQ 8192
#define BATCH 4
#define LI 77
#define MMHID 1024
#define LN_EPS 1e-5f
#define SCALE_QK 0.03608439182435161f  // 1/sqrt(768)

typedef __attribute__((ext_vector_type(8))) short short8v;
typedef __attribute__((ext_vector_type(4))) float f32x4;
typedef __attribute__((ext_vector_type(8))) unsigned short u16x8;

#define AS1 __attribute__((address_space(1)))
#define AS3 __attribute__((address_space(3)))

__device__ inline unsigned short f2bf(float f) {
    unsigned u = __float_as_uint(f);
    u += 0x7fffu + ((u >> 16) & 1u);
    return (unsigned short)(u >> 16);
}
__device__ inline float bf2f(unsigned short h) {
    return __uint_as_float(((unsigned)h) << 16);
}

// ---------------- block reduce (256 threads, 4 waves) ----------------
__device__ inline void block_reduce2_256(float& s1, float& s2, float* sm) {
    #pragma unroll
    for (int o = 32; o; o >>= 1) { s1 += __shfl_down(s1, o); s2 += __shfl_down(s2, o); }
    int lane = threadIdx.x & 63, w = threadIdx.x >> 6;
    __syncthreads();
    if (lane == 0) { sm[w] = s1; sm[4 + w] = s2; }
    __syncthreads();
    s1 = sm[0] + sm[1] + sm[2] + sm[3];
    s2 = sm[4] + sm[5] + sm[6] + sm[7];
}

// ---------------- f32 -> bf16 convert (vectorized) ----------------
__global__ __launch_bounds__(256) void cvt_kernel(const float* __restrict__ in,
                                                  unsigned short* __restrict__ out, int n8) {
    int i = blockIdx.x * 256 + threadIdx.x;
    if (i >= n8) return;
    const float4* p = (const float4*)(in + (size_t)i * 8);
    float4 a = p[0], b = p[1];
    u16x8 o;
    o[0] = f2bf(a.x); o[1] = f2bf(a.y); o[2] = f2bf(a.z); o[3] = f2bf(a.w);
    o[4] = f2bf(b.x); o[5] = f2bf(b.y); o[6] = f2bf(b.z); o[7] = f2bf(b.w);
    *(u16x8*)(out + (size_t)i * 8) = o;
}

// ---------------- W_kv_mm (1024x1536) -> Wt bf16 (1536x1024) ----------------
__global__ __launch_bounds__(256) void transW_kernel(const float* __restrict__ W,
                                                     unsigned short* __restrict__ Wt) {
    __shared__ float tile[32][33];
    int n0 = blockIdx.x * 32, k0 = blockIdx.y * 32;
    int tx = threadIdx.x, ty = threadIdx.y;
    #pragma unroll
    for (int i = 0; i < 32; i += 8)
        tile[ty + i][tx] = W[(size_t)(k0 + ty + i) * 1536 + n0 + tx];
    __syncthreads();
    #pragma unroll
    for (int i = 0; i < 32; i += 8)
        Wt[(size_t)(n0 + ty + i) * 1024 + k0 + tx] = f2bf(tile[tx][ty + i]);
}

// ---------------- big GEMM: A(32768x1024)bf16 @ Bt(1536x1024)bf16^T + bias -> C bf16 ----------------
// 128x128 tile, BK=64, 4 waves (2x2), global_load_lds staging, XOR-swizzled LDS.
#define GM 32768
#define GN 1536
#define GK 1024

__global__ __launch_bounds__(256) void gemm_kv_kernel(const unsigned short* __restrict__ A,
                                                      const unsigned short* __restrict__ Bt,
                                                      const float* __restrict__ bias,
                                                      unsigned short* __restrict__ C) {
    __shared__ unsigned short sA[128 * 64];
    __shared__ unsigned short sB[128 * 64];

    int nwg = gridDim.x;
    int bid = blockIdx.x;
    int wg = bid;
    if ((nwg & 7) == 0) { int cpx = nwg >> 3; wg = (bid & 7) * cpx + (bid >> 3); }
    int bm = wg / (GN / 128), bn = wg % (GN / 128);
    int row0 = bm * 128, col0 = bn * 128;

    int tid = threadIdx.x;
    int lane = tid & 63, wid = tid >> 6;
    int wr = wid >> 1, wc = wid & 1;

    f32x4 acc[4][4] = {};

    // staging geometry: chunk ch = wid*4+i covers LDS bytes [ch*1024, ch*1024+1024)
    // linear pos p = ch*1024 + lane*16 ; r = p/128 ; source col = ((lane&7) ^ (r&7))*8
    int rS[4], cS[4];
    #pragma unroll
    for (int i = 0; i < 4; i++) {
        int ch = wid * 4 + i;
        int r = ch * 8 + (lane >> 3);
        rS[i] = r;
        cS[i] = ((lane & 7) ^ (r & 7)) << 3;
    }

    for (int k0 = 0; k0 < GK; k0 += 64) {
        #pragma unroll
        for (int i = 0; i < 4; i++) {
            int ch = wid * 4 + i;
            const unsigned short* ga = A + (size_t)(row0 + rS[i]) * GK + k0 + cS[i];
            __builtin_amdgcn_global_load_lds((const AS1 unsigned int*)ga,
                                             (AS3 unsigned int*)&sA[ch * 512], 16, 0, 0);
            const unsigned short* gb = Bt + (size_t)(col0 + rS[i]) * GK + k0 + cS[i];
            __builtin_amdgcn_global_load_lds((const AS1 unsigned int*)gb,
                                             (AS3 unsigned int*)&sB[ch * 512], 16, 0, 0);
        }
        __syncthreads();

        #pragma unroll
        for (int kk = 0; kk < 64; kk += 32) {
            int ko = (kk + ((lane >> 4) << 3)) * 2;  // byte offset of this lane's k-slice
            short8v af[4], bf[4];
            #pragma unroll
            for (int m = 0; m < 4; m++) {
                int r = wr * 64 + m * 16 + (lane & 15);
                int addr = r * 128 + (ko ^ ((r & 7) << 4));
                af[m] = *(const short8v*)((const char*)sA + addr);
            }
            #pragma unroll
            for (int n = 0; n < 4; n++) {
                int r = wc * 64 + n * 16 + (lane & 15);
                int addr = r * 128 + (ko ^ ((r & 7) << 4));
                bf[n] = *(const short8v*)((const char*)sB + addr);
            }
            #pragma unroll
            for (int m = 0; m < 4; m++)
                #pragma unroll
                for (int n = 0; n < 4; n++)
                    acc[m][n] = __builtin_amdgcn_mfma_f32_16x16x32_bf16(af[m], bf[n], acc[m][n], 0, 0, 0);
        }
        __syncthreads();
    }

    int crow = (lane >> 4) * 4;
    int ccol = lane & 15;
    #pragma unroll
    for (int m = 0; m < 4; m++) {
        #pragma unroll
        for (int n = 0; n < 4; n++) {
            int gc = col0 + wc * 64 + n * 16 + ccol;
            float bv = bias[gc];
            #pragma unroll
            for (int j = 0; j < 4; j++) {
                int gr = row0 + wr * 64 + m * 16 + crow + j;
                C[(size_t)gr * GN + gc] = f2bf(acc[m][n][j] + bv);
            }
        }
    }
}

// ---------------- LN over 768 (bf16 in-place), one block per (row, half) ----------------
__global__ __launch_bounds__(256) void ln_bf16_kernel(unsigned short* __restrict__ kv,
                                                      const float* __restrict__ g,
                                                      const float* __restrict__ b) {
    int rh = blockIdx.x;
    unsigned short* p = kv + (size_t)(rh >> 1) * 1536 + (rh & 1) * 768;
    int t = threadIdx.x;
    float x0 = bf2f(p[t]), x1 = bf2f(p[t + 256]), x2 = bf2f(p[t + 512]);
    float s = x0 + x1 + x2, s2 = x0 * x0 + x1 * x1 + x2 * x2;
    __shared__ float sm[8];
    block_reduce2_256(s, s2, sm);
    float mu = s * (1.f / 768.f);
    float var = s2 * (1.f / 768.f) - mu * mu;
    float inv = rsqrtf(var + LN_EPS);
    p[t]       = f2bf((x0 - mu) * inv * g[t]       + b[t]);
    p[t + 256] = f2bf((x1 - mu) * inv * g[t + 256] + b[t + 256]);
    p[t + 512] = f2bf((x2 - mu) * inv * g[t + 512] + b[t + 512]);
}

// ---------------- LN over 768 (f32 in-place) ----------------
__global__ __launch_bounds__(256) void ln_f32_kernel(float* __restrict__ kv,
                                                     const float* __restrict__ g,
                                                     const float* __restrict__ b) {
    int rh = blockIdx.x;
    float* p = kv + (size_t)(rh >> 1) * 1536 + (rh & 1) * 768;
    int t = threadIdx.x;
    float x0 = p[t], x1 = p[t + 256], x2 = p[t + 512];
    float s = x0 + x1 + x2, s2 = x0 * x0 + x1 * x1 + x2 * x2;
    __shared__ float sm[8];
    block_reduce2_256(s, s2, sm);
    float mu = s * (1.f / 768.f);
    float var = s2 * (1.f / 768.f) - mu * mu;
    float inv = rsqrtf(var + LN_EPS);
    p[t]       = (x0 - mu) * inv * g[t]       + b[t];
    p[t + 256] = (x1 - mu) * inv * g[t + 256] + b[t + 256];
    p[t + 512] = (x2 - mu) * inv * g[t + 512] + b[t + 512];
}

// ---------------- small row-block GEMM: OUT[r] = (LN?)(X[r] @ W + bias), W is D x C f32 ----------------
template <int C, int RPB, bool DO_LN>
__global__ __launch_bounds__(256) void rowgemm_kernel(const float* __restrict__ X,
                                                      const float* __restrict__ W,
                                                      const float* __restrict__ bias,
                                                      const float* __restrict__ lng,
                                                      const float* __restrict__ lnb,
                                                      float* __restrict__ OUT, int D) {
    __shared__ float xs[RPB][HIDDEN];
    __shared__ float sm[8];
    int t = threadIdx.x;
    int r0 = blockIdx.x * RPB;
    for (int r = 0; r < RPB; r++)
        for (int d = t; d < D; d += 256) xs[r][d] = X[(size_t)(r0 + r) * D + d];
    __syncthreads();

    constexpr int NC = C / 256;
    float acc[RPB][NC] = {};
    for (int d = 0; d < D; ++d) {
        const float* wrow = W + (size_t)d * C;
        float wv[NC];
        #pragma unroll
        for (int i = 0; i < NC; i++) wv[i] = wrow[t + i * 256];
        #pragma unroll
        for (int r = 0; r < RPB; r++) {
            float xv = xs[r][d];
            #pragma unroll
            for (int i = 0; i < NC; i++) acc[r][i] = fmaf(xv, wv[i], acc[r][i]);
        }
    }
    for (int r = 0; r < RPB; r++) {
        float y[NC];
        #pragma unroll
        for (int i = 0; i < NC; i++) y[i] = acc[r][i] + bias[t + i * 256];
        if (DO_LN) {
            float s = 0, s2 = 0;
            #pragma unroll
            for (int i = 0; i < NC; i++) { s += y[i]; s2 += y[i] * y[i]; }
            block_reduce2_256(s, s2, sm);
            float mu = s * (1.f / (float)C);
            float var = s2 * (1.f / (float)C) - mu * mu;
            float inv = rsqrtf(var + LN_EPS);
            #pragma unroll
            for (int i = 0; i < NC; i++)
                y[i] = (y[i] - mu) * inv * lng[t + i * 256] + lnb[t + i * 256];
        }
        float* orow = OUT + (size_t)(r0 + r) * C;
        #pragma unroll
        for (int i = 0; i < NC; i++) orow[t + i * 256] = y[i];
    }
}

// ---------------- inst attention: q(64x768) x k_inst(77x768) -> softmax -> @ v_inst ----------------
__global__ __launch_bounds__(256) void attn_inst_kernel(const float* __restrict__ queries,
                                                        const float* __restrict__ kv,  // b x 77 x 1536 (LN'd)
                                                        float* __restrict__ qatt) {    // b x 64 x 768
    int bidx = blockIdx.x;
    int b = bidx >> 6, n = bidx & 63;
    __shared__ float qs[HIDDEN];
    __shared__ float sc[LI], sc2[LI];
    int t = threadIdx.x, lane = t & 63, w = t >> 6;
    const float* q = queries + (size_t)n * HIDDEN;
    for (int d = t; d < HIDDEN; d += 256) qs[d] = q[d];
    __syncthreads();
    const float* kb = kv + (size_t)b * LI * 1536;
    for (int j = w; j < LI; j += 4) {
        const float* kr = kb + (size_t)j * 1536;
        float a = 0;
        #pragma unroll
        for (int i = 0; i < 12; i++) { int d = lane + i * 64; a = fmaf(kr[d], qs[d], a); }
        #pragma unroll
        for (int o = 32; o; o >>= 1) a += __shfl_down(a, o);
        if (lane == 0) sc[j] = a * SCALE_QK;
    }
    __syncthreads();
    float m = -1e30f;
    for (int j = 0; j < LI; j++) m = fmaxf(m, sc[j]);
    if (t < LI) sc2[t] = expf(sc[t] - m);
    __syncthreads();
    float s = 0;
    for (int j = 0; j < LI; j++) s += sc2[j];
    float inv = 1.f / s;
    float o0 = 0, o1 = 0, o2 = 0;
    for (int j = 0; j < LI; j++) {
        float p = sc2[j] * inv;
        const float* vr = kb + (size_t)j * 1536 + 768;
        o0 = fmaf(p, vr[t], o0);
        o1 = fmaf(p, vr[t + 256], o1);
        o2 = fmaf(p, vr[t + 512], o2);
    }
    float* orow = qatt + ((size_t)b * NQ + n) * HIDDEN;
    orow[t] = o0; orow[t + 256] = o1; orow[t + 512] = o2;
}

// ---------------- windowed attention over bf16 k/v (4x8192x1536, LN'd) ----------------
__global__ __launch_bounds__(512) void window_attn_kernel(const float* __restrict__ q2,
                                                          const unsigned short* __restrict__ kv,
                                                          float* __restrict__ out) {
    int bidx = blockIdx.x;
    int b = bidx >> 6, n = bidx & 63;
    int step = (MSEQ - WINSZ) / (NQ - 1);  // 121
    int s = n * step;
    if (s + WINSZ > MSEQ) s = MSEQ - WINSZ;

    __shared__ float qs[HIDDEN];
    __shared__ float p[WINSZ];
    __shared__ float sm[8];
    int t = threadIdx.x, lane = t & 63, w = t >> 6;
    const float* q = q2 + ((size_t)b * NQ + n) * HIDDEN;
    if (t < 256) { qs[t] = q[t]; qs[t + 256] = q[t + 256]; qs[t + 512] = q[t + 512]; }
    __syncthreads();

    // scores: thread t owns window slot t
    const unsigned short* krow = kv + (size_t)(b * MSEQ + s + t) * 1536;
    float a = 0;
    for (int d = 0; d < HIDDEN; d += 8) {
        u16x8 k8 = *(const u16x8*)(krow + d);
        #pragma unroll
        for (int j = 0; j < 8; j++) a = fmaf(bf2f(k8[j]), qs[d + j], a);
    }
    a *= SCALE_QK;

    // block softmax over 512
    float m = a;
    #pragma unroll
    for (int o = 32; o; o >>= 1) m = fmaxf(m, __shfl_down(m, o));
    if (lane == 0) sm[w] = m;
    __syncthreads();
    m = sm[0];
    #pragma unroll
    for (int i = 1; i < 8; i++) m = fmaxf(m, sm[i]);
    float e = expf(a - m);
    float ssum = e;
    #pragma unroll
    for (int o = 32; o; o >>= 1) ssum += __shfl_down(ssum, o);
    __syncthreads();
    if (lane == 0) sm[w] = ssum;
    __syncthreads();
    ssum = 0;
    #pragma unroll
    for (int i = 0; i < 8; i++) ssum += sm[i];
    p[t] = e / ssum;
    __syncthreads();

    // PV: threads 0..511 own d=t; threads 0..255 additionally own d=512+t
    const unsigned short* vbase = kv + (size_t)(b * MSEQ + s) * 1536 + 768;
    float o0 = 0, o1 = 0;
    for (int wv = 0; wv < WINSZ; ++wv) {
        float pw = p[wv];
        const unsigned short* vr = vbase + (size_t)wv * 1536;
        o0 = fmaf(pw, bf2f(vr[t]), o0);
        if (t < 256) o1 = fmaf(pw, bf2f(vr[512 + t]), o1);
    }
    float* orow = out + ((size_t)b * NQ + n) * HIDDEN;
    orow[t] = o0;
    if (t < 256) orow[512 + t] = o1;
}

// ---------------- host launch ----------------
extern "C" void kernel_launch(void* const* d_in, const int* in_sizes, int n_in,
                              void* d_out, int out_size, void* d_ws, size_t ws_size,
                              hipStream_t stream) {
    (void)in_sizes; (void)n_in; (void)out_size; (void)ws_size;
    const float* x_mm    = (const float*)d_in[0];
    const float* instf   = (const float*)d_in[1];
    const float* queries = (const float*)d_in[2];
    const float* W_proj  = (const float*)d_in[3];
    const float* b_proj  = (const float*)d_in[4];
    const float* W_kvi   = (const float*)d_in[5];
    const float* b_kvi   = (const float*)d_in[6];
    const float* W_oi    = (const float*)d_in[7];
    const float* b_oi    = (const float*)d_in[8];
    const float* W_kvm   = (const float*)d_in[9];
    const float* b_kvm   = (const float*)d_in[10];
    const float* W_om    = (const float*)d_in[11];
    const float* b_om    = (const float*)d_in[12];
    const float* ln_g    = (const float*)d_in[13];
    const float* ln_b    = (const float*)d_in[14];
    float* out = (float*)d_out;

    char* ws = (char*)d_ws;
    size_t off = 0;
    auto carve = [&](size_t bytes) -> char* {
        char* p = ws + off;
        off += (bytes + 255) & ~(size_t)255;
        return p;
    };
    unsigned short* x_bf  = (unsigned short*)carve((size_t)BATCH * MSEQ * MMHID * 2);
    unsigned short* wt_bf = (unsigned short*)carve((size_t)2 * HIDDEN * MMHID * 2);
    unsigned short* kv_mm = (unsigned short*)carve((size_t)BATCH * MSEQ * 2 * HIDDEN * 2);
    float* inst    = (float*)carve((size_t)BATCH * LI * HIDDEN * 4);
    float* kv_inst = (float*)carve((size_t)BATCH * LI * 2 * HIDDEN * 4);
    float* q_att   = (float*)carve((size_t)BATCH * NQ * HIDDEN * 4);
    float* q2      = (float*)carve((size_t)BATCH * NQ * HIDDEN * 4);
    float* a_out   = (float*)carve((size_t)BATCH * NQ * HIDDEN * 4);

    // ---- mm branch ----
    int n8 = BATCH * MSEQ * MMHID / 8;
    cvt_kernel<<<(n8 + 255) / 256, 256, 0, stream>>>(x_mm, x_bf, n8);
    transW_kernel<<<dim3(1536 / 32, 1024 / 32), dim3(32, 8), 0, stream>>>(W_kvm, wt_bf);
    gemm_kv_kernel<<<(GM / 128) * (GN / 128), 256, 0, stream>>>(x_bf, wt_bf, b_kvm, kv_mm);
    ln_bf16_kernel<<<BATCH * MSEQ * 2, 256, 0, stream>>>(kv_mm, ln_g, ln_b);

    // ---- inst branch ----
    rowgemm_kernel<768, 4, false><<<(BATCH * LI) / 4, 256, 0, stream>>>(instf, W_proj, b_proj, nullptr, nullptr, inst, HIDDEN);
    rowgemm_kernel<1536, 4, false><<<(BATCH * LI) / 4, 256, 0, stream>>>(inst, W_kvi, b_kvi, nullptr, nullptr, kv_inst, HIDDEN);
    ln_f32_kernel<<<BATCH * LI * 2, 256, 0, stream>>>(kv_inst, ln_g, ln_b);
    attn_inst_kernel<<<BATCH * NQ, 256, 0, stream>>>(queries, kv_inst, q_att);
    rowgemm_kernel<768, 4, true><<<(BATCH * NQ) / 4, 256, 0, stream>>>(q_att, W_oi, b_oi, ln_g, ln_b, q2, HIDDEN);

    // ---- windowed attention + output projection ----
    window_attn_kernel<<<BATCH * NQ, 512, 0, stream>>>(q2, kv_mm, a_out);
    rowgemm_kernel<768, 4, true><<<(BATCH * NQ) / 4, 256, 0, stream>>>(a_out, W_om, b_om, ln_g, ln_b, out, HIDDEN);
}